// Round 1
// baseline (1377.963 us; speedup 1.0000x reference)
//
#include <hip/hip_runtime.h>
#include <math.h>

#define BB 2
#define NN 8192
#define DD 512
#define HH 8
#define DK 64
#define KNB 32
#define BN (BB*NN)          // 16384 rows
#define BHN (BB*HH*NN)      // 131072 (b,h,n) tuples
#define TSLAB ((size_t)BB*HH*NN*DK)  // 8388608 floats per tensor

// ---------------- Kernel 1: QKV projection ----------------
// C[row, c] = sum_d x[row,d] * W[c,d]  for W in {Wq,Wk,Wv}
// 16 rows per block, 256 threads, 6 column passes of 256.
// x tile in LDS; all lanes read the same LDS address per FMA -> broadcast, conflict-free.
__global__ __launch_bounds__(256) void qkv_proj(
    const float* __restrict__ x,
    const float* __restrict__ Wq, const float* __restrict__ Wk, const float* __restrict__ Wv,
    float* __restrict__ Qb, float* __restrict__ Kb, float* __restrict__ Vb)
{
    __shared__ float xs[16][512];
    const int tid = threadIdx.x;
    const int row0 = blockIdx.x * 16;
    for (int i = tid; i < 16 * 512; i += 256)
        xs[i >> 9][i & 511] = x[(size_t)row0 * 512 + i];
    __syncthreads();

    #pragma unroll 1
    for (int pass = 0; pass < 6; ++pass) {
        const int c = pass * 256 + tid;           // 0..1535, wave-uniform W selection
        const float* W   = (c < 512) ? Wq : (c < 1024) ? Wk : Wv;
        float*       Out = (c < 512) ? Qb : (c < 1024) ? Kb : Vb;
        const int cc = c & 511;
        const float4* w4 = (const float4*)(W + (size_t)cc * 512);
        float acc[16];
        #pragma unroll
        for (int r = 0; r < 16; ++r) acc[r] = 0.f;
        for (int d4 = 0; d4 < 128; ++d4) {
            const float4 w = w4[d4];
            #pragma unroll
            for (int r = 0; r < 16; ++r) {
                const float4 xv = *(const float4*)(&xs[r][d4 << 2]);
                acc[r] = fmaf(w.x, xv.x, acc[r]);
                acc[r] = fmaf(w.y, xv.y, acc[r]);
                acc[r] = fmaf(w.z, xv.z, acc[r]);
                acc[r] = fmaf(w.w, xv.w, acc[r]);
            }
        }
        const int h = cc >> 6, d = cc & 63;
        #pragma unroll
        for (int r = 0; r < 16; ++r) {
            const int row = row0 + r;
            const int b = row >> 13, nn = row & 8191;
            Out[((size_t)(b * HH + h) * NN + nn) * DK + d] = acc[r];
        }
    }
}

// ---------------- Kernel 2: per-head LayerNorm of Q and K (in place) ----------------
// One wave (64 lanes) per (b,h,n) group of 64 elements; does Q then K.
__global__ __launch_bounds__(256) void ln_qk(float* __restrict__ Qb, float* __restrict__ Kb)
{
    const int wid  = (int)((blockIdx.x * 256 + threadIdx.x) >> 6);  // 0..BHN-1
    const int lane = threadIdx.x & 63;
    float* bufs[2] = {Qb, Kb};
    #pragma unroll
    for (int t = 0; t < 2; ++t) {
        float* p = bufs[t] + (size_t)wid * 64;
        const float v = p[lane];
        float s = v;
        for (int off = 32; off; off >>= 1) s += __shfl_xor(s, off);
        const float mu = s * (1.f / 64.f);
        const float dv = v - mu;
        float q = dv * dv;
        for (int off = 32; off; off >>= 1) q += __shfl_xor(q, off);
        const float var = q * (1.f / 64.f);
        p[lane] = dv * rsqrtf(var + 1e-5f);
    }
}

// ---------------- Kernel 3: gather-attention ----------------
// One wave per (b,h,n). Lanes 0..31 each own one neighbor: full 64-dot score.
// Wave softmax, then lane d accumulates sum_k p_k * V[g_k][d] (coalesced 256B loads).
__global__ __launch_bounds__(256) void attn(
    const float* __restrict__ Qb, const float* __restrict__ Kb, const float* __restrict__ Vb,
    const int* __restrict__ idx, float* __restrict__ Ob)
{
    const int wid  = (int)((blockIdx.x * 256 + threadIdx.x) >> 6);  // 0..BHN-1
    const int lane = threadIdx.x & 63;
    const int bh = wid >> 13;     // 0..15
    const int n  = wid & 8191;
    const size_t base = (size_t)bh * NN * DK;

    int g = 0;
    if (lane < KNB) g = idx[n * KNB + lane];

    float s = -INFINITY;
    if (lane < KNB) {
        const float4* qr = (const float4*)(Qb + base + (size_t)n * DK);
        const float4* kr = (const float4*)(Kb + base + (size_t)g * DK);
        float acc = 0.f;
        #pragma unroll
        for (int i = 0; i < 16; ++i) {
            const float4 a = qr[i], b4 = kr[i];
            acc = fmaf(a.x, b4.x, acc); acc = fmaf(a.y, b4.y, acc);
            acc = fmaf(a.z, b4.z, acc); acc = fmaf(a.w, b4.w, acc);
        }
        s = acc * 0.125f;   // 1/sqrt(64)
    }
    float m = s;
    for (int off = 32; off; off >>= 1) m = fmaxf(m, __shfl_xor(m, off));
    const float e = (lane < KNB) ? __expf(s - m) : 0.f;
    float tot = e;
    for (int off = 32; off; off >>= 1) tot += __shfl_xor(tot, off);
    const float p = e / tot;

    float o = 0.f;
    #pragma unroll 1
    for (int k = 0; k < KNB; ++k) {
        const int   gk = __shfl(g, k);
        const float pk = __shfl(p, k);
        o = fmaf(pk, Vb[base + (size_t)gk * DK + lane], o);
    }
    const int b = bh >> 3, h = bh & 7;
    Ob[((size_t)(b * NN + n)) * DD + h * DK + lane] = o;
}

// ---------------- Kernel 4: output projection ----------------
__global__ __launch_bounds__(256) void out_proj(
    const float* __restrict__ Ob, const float* __restrict__ Wout,
    const float* __restrict__ bout, float* __restrict__ out)
{
    __shared__ float xs[16][512];
    const int tid = threadIdx.x;
    const int row0 = blockIdx.x * 16;
    for (int i = tid; i < 16 * 512; i += 256)
        xs[i >> 9][i & 511] = Ob[(size_t)row0 * 512 + i];
    __syncthreads();

    #pragma unroll 1
    for (int pass = 0; pass < 2; ++pass) {
        const int c = pass * 256 + tid;
        const float4* w4 = (const float4*)(Wout + (size_t)c * 512);
        float acc[16];
        #pragma unroll
        for (int r = 0; r < 16; ++r) acc[r] = 0.f;
        for (int d4 = 0; d4 < 128; ++d4) {
            const float4 w = w4[d4];
            #pragma unroll
            for (int r = 0; r < 16; ++r) {
                const float4 xv = *(const float4*)(&xs[r][d4 << 2]);
                acc[r] = fmaf(w.x, xv.x, acc[r]);
                acc[r] = fmaf(w.y, xv.y, acc[r]);
                acc[r] = fmaf(w.z, xv.z, acc[r]);
                acc[r] = fmaf(w.w, xv.w, acc[r]);
            }
        }
        const float bb = bout[c];
        #pragma unroll
        for (int r = 0; r < 16; ++r)
            out[((size_t)(row0 + r)) * 512 + c] = acc[r] + bb;
    }
}

extern "C" void kernel_launch(void* const* d_in, const int* in_sizes, int n_in,
                              void* d_out, int out_size, void* d_ws, size_t ws_size,
                              hipStream_t stream)
{
    const float* x    = (const float*)d_in[0];
    const int*   idx  = (const int*)  d_in[1];
    const float* Wq   = (const float*)d_in[2];
    const float* Wk   = (const float*)d_in[3];
    const float* Wv   = (const float*)d_in[4];
    const float* Wout = (const float*)d_in[5];
    const float* bout = (const float*)d_in[6];

    float* ws = (float*)d_ws;
    float* Qb = ws;
    float* Kb = ws + TSLAB;
    float* Vb = ws + 2 * TSLAB;
    float* Ob = ws + 3 * TSLAB;
    float* out = (float*)d_out;

    qkv_proj<<<BN / 16, 256, 0, stream>>>(x, Wq, Wk, Wv, Qb, Kb, Vb);
    ln_qk   <<<BHN / 4, 256, 0, stream>>>(Qb, Kb);
    attn    <<<BHN / 4, 256, 0, stream>>>(Qb, Kb, Vb, idx, Ob);
    out_proj<<<BN / 16, 256, 0, stream>>>(Ob, Wout, bout, out);
}

// Round 2
// 515.142 us; speedup vs baseline: 2.6749x; 2.6749x over previous
//
#include <hip/hip_runtime.h>
#include <hip/hip_bf16.h>
#include <math.h>

#define BB 2
#define NN 8192
#define DD 512
#define HH 8
#define DK 64
#define KNB 32
#define BN (BB*NN)          // 16384 rows
#define BHN (BB*HH*NN)      // 131072 (b,h,n) tuples

typedef __attribute__((ext_vector_type(8))) short bf16x8;   // 8 bf16 in 4 VGPRs
typedef __attribute__((ext_vector_type(4))) float f32x4;

// async global->LDS, 16B per lane. LDS dest must be wave-uniform base; HW adds lane*16.
__device__ __forceinline__ void gload_lds16(const void* gptr, void* lptr) {
    __builtin_amdgcn_global_load_lds(
        (const __attribute__((address_space(1))) unsigned int*)gptr,
        (__attribute__((address_space(3))) unsigned int*)lptr,
        16, 0, 0);
}

// ---------------- fp32 -> bf16 converters ----------------
__global__ __launch_bounds__(256) void cvt_x(const float* __restrict__ in,
                                             unsigned short* __restrict__ out) {
    const int i = (blockIdx.x * 256 + threadIdx.x) * 4;   // over BN*DD = 8388608
    const float4 v = *(const float4*)(in + i);
    ushort4 u;
    u.x = __bfloat16_as_ushort(__float2bfloat16(v.x));
    u.y = __bfloat16_as_ushort(__float2bfloat16(v.y));
    u.z = __bfloat16_as_ushort(__float2bfloat16(v.z));
    u.w = __bfloat16_as_ushort(__float2bfloat16(v.w));
    *(ushort4*)(out + i) = u;
}

__global__ __launch_bounds__(256) void cvt_w(const float* __restrict__ Wq, const float* __restrict__ Wk,
                                             const float* __restrict__ Wv, const float* __restrict__ Wo,
                                             unsigned short* __restrict__ Wfb,
                                             unsigned short* __restrict__ Wob) {
    const int e = (blockIdx.x * 256 + threadIdx.x) * 4;   // over 4*262144
    const int t = e >> 18;
    const int off = e & 262143;
    const float* src = (t == 0) ? Wq : (t == 1) ? Wk : (t == 2) ? Wv : Wo;
    unsigned short* dst = (t < 3) ? (Wfb + (size_t)t * 262144) : Wob;
    const float4 v = *(const float4*)(src + off);
    ushort4 u;
    u.x = __bfloat16_as_ushort(__float2bfloat16(v.x));
    u.y = __bfloat16_as_ushort(__float2bfloat16(v.y));
    u.z = __bfloat16_as_ushort(__float2bfloat16(v.z));
    u.w = __bfloat16_as_ushort(__float2bfloat16(v.w));
    *(ushort4*)(dst + off) = u;
}

// ---------------- Kernel 1: fused QKV projection, bf16 MFMA ----------------
// C[row, c] = sum_d X[row,d] * W[c,d], M=16384, N=1536 (Q|K|V), K=512.
// m97 structure: 128x128 tile, BK=32, global_load_lds width 16, 4 waves in 2x2.
// Epilogue scatters into (b,h,n,d) fp32 slabs.
__global__ __launch_bounds__(256) void gemm_qkv(
    const unsigned short* __restrict__ Xb, const unsigned short* __restrict__ Wfb,
    float* __restrict__ Qb, float* __restrict__ Kb, float* __restrict__ Vb)
{
    __shared__ unsigned short Als[128 * 32];   // 8 KB
    __shared__ unsigned short Bls[128 * 32];   // 8 KB
    const int tid  = threadIdx.x;
    const int wave = tid >> 6, lane = tid & 63;
    const int wm = wave >> 1, wn = wave & 1;
    const int quad = lane >> 4, r = lane & 15;
    const int row0 = blockIdx.x * 128;
    const int c0   = blockIdx.y * 128;        // 0..1535, 128 | 512 so tile is within one tensor

    f32x4 acc[4][4];
    #pragma unroll
    for (int i = 0; i < 4; ++i)
        #pragma unroll
        for (int j = 0; j < 4; ++j) acc[i][j] = (f32x4)0.f;

    const char* Ab = (const char*)Xb;
    const char* Bb = (const char*)Wfb;

    for (int k0 = 0; k0 < 512; k0 += 32) {
        __syncthreads();   // prior iter's LDS reads complete
        #pragma unroll
        for (int q = 0; q < 2; ++q) {
            const int li = q * 4096 + wave * 1024 + lane * 16;  // byte index in 8 KB tile
            const int rr = li >> 6, off = li & 63;              // 64 B per 32-bf16 row
            gload_lds16(Ab + (size_t)(row0 + rr) * 1024 + k0 * 2 + off,
                        (char*)Als + (q * 4096 + wave * 1024));
            gload_lds16(Bb + (size_t)(c0 + rr) * 1024 + k0 * 2 + off,
                        (char*)Bls + (q * 4096 + wave * 1024));
        }
        __syncthreads();   // staging visible (vmcnt drained by barrier)

        bf16x8 af[4], bf[4];
        #pragma unroll
        for (int i = 0; i < 4; ++i)
            af[i] = *(const bf16x8*)(&Als[(wm * 64 + i * 16 + r) * 32 + quad * 8]);
        #pragma unroll
        for (int j = 0; j < 4; ++j)
            bf[j] = *(const bf16x8*)(&Bls[(wn * 64 + j * 16 + r) * 32 + quad * 8]);
        #pragma unroll
        for (int i = 0; i < 4; ++i)
            #pragma unroll
            for (int j = 0; j < 4; ++j)
                acc[i][j] = __builtin_amdgcn_mfma_f32_16x16x32_bf16(af[i], bf[j], acc[i][j], 0, 0, 0);
    }

    // Epilogue: C/D layout col=lane&15, row=quad*4+reg (verified m89).
    const int tensor = c0 >> 9;                       // block-uniform
    float* Out = (tensor == 0) ? Qb : (tensor == 1) ? Kb : Vb;
    #pragma unroll
    for (int i = 0; i < 4; ++i) {
        #pragma unroll
        for (int j = 0; j < 4; ++j) {
            const int colg = c0 + wn * 64 + j * 16 + r;   // global col 0..1535
            const int cc = colg & 511;
            const int h = cc >> 6, d = cc & 63;
            #pragma unroll
            for (int reg = 0; reg < 4; ++reg) {
                const int row = row0 + wm * 64 + i * 16 + quad * 4 + reg;
                const int b = row >> 13, n = row & 8191;
                Out[(((size_t)(b * HH + h) * NN + n) << 6) + d] = acc[i][j][reg];
            }
        }
    }
}

// ---------------- Kernel 2: per-head LayerNorm of Q and K (in place, fp32) ----------------
__global__ __launch_bounds__(256) void ln_qk(float* __restrict__ Qb, float* __restrict__ Kb)
{
    const int wid  = (int)((blockIdx.x * 256 + threadIdx.x) >> 6);
    const int lane = threadIdx.x & 63;
    float* bufs[2] = {Qb, Kb};
    #pragma unroll
    for (int t = 0; t < 2; ++t) {
        float* p = bufs[t] + (size_t)wid * 64;
        const float v = p[lane];
        float s = v;
        for (int off = 32; off; off >>= 1) s += __shfl_xor(s, off);
        const float mu = s * (1.f / 64.f);
        const float dv = v - mu;
        float q = dv * dv;
        for (int off = 32; off; off >>= 1) q += __shfl_xor(q, off);
        const float var = q * (1.f / 64.f);
        p[lane] = dv * rsqrtf(var + 1e-5f);
    }
}

// ---------------- Kernel 3: gather-attention (fp32 math, bf16 output) ----------------
__global__ __launch_bounds__(256) void attn(
    const float* __restrict__ Qb, const float* __restrict__ Kb, const float* __restrict__ Vb,
    const int* __restrict__ idx, unsigned short* __restrict__ Ob)
{
    const int wid  = (int)((blockIdx.x * 256 + threadIdx.x) >> 6);
    const int lane = threadIdx.x & 63;
    const int bh = wid >> 13;
    const int n  = wid & 8191;
    const size_t base = (size_t)bh * NN * DK;

    int g = 0;
    if (lane < KNB) g = idx[n * KNB + lane];

    float s = -INFINITY;
    if (lane < KNB) {
        const float4* qr = (const float4*)(Qb + base + (size_t)n * DK);
        const float4* kr = (const float4*)(Kb + base + (size_t)g * DK);
        float acc = 0.f;
        #pragma unroll
        for (int i = 0; i < 16; ++i) {
            const float4 a = qr[i], b4 = kr[i];
            acc = fmaf(a.x, b4.x, acc); acc = fmaf(a.y, b4.y, acc);
            acc = fmaf(a.z, b4.z, acc); acc = fmaf(a.w, b4.w, acc);
        }
        s = acc * 0.125f;   // 1/sqrt(64)
    }
    float m = s;
    for (int off = 32; off; off >>= 1) m = fmaxf(m, __shfl_xor(m, off));
    const float e = (lane < KNB) ? __expf(s - m) : 0.f;
    float tot = e;
    for (int off = 32; off; off >>= 1) tot += __shfl_xor(tot, off);
    const float p = e / tot;

    float o = 0.f;
    #pragma unroll 1
    for (int k = 0; k < KNB; ++k) {
        const int   gk = __shfl(g, k);
        const float pk = __shfl(p, k);
        o = fmaf(pk, Vb[base + (size_t)gk * DK + lane], o);
    }
    const int b = bh >> 3, h = bh & 7;
    Ob[((size_t)(b * NN + n)) * DD + h * DK + lane] =
        __bfloat16_as_ushort(__float2bfloat16(o));
}

// ---------------- Kernel 4: output projection, bf16 MFMA ----------------
// C[row,c] = sum_d Ob[row,d]*Wo[c,d] + bout[c]; M=16384, N=512, K=512. fp32 out.
__global__ __launch_bounds__(256) void gemm_out(
    const unsigned short* __restrict__ Ob, const unsigned short* __restrict__ Wob,
    const float* __restrict__ bout, float* __restrict__ out)
{
    __shared__ unsigned short Als[128 * 32];
    __shared__ unsigned short Bls[128 * 32];
    const int tid  = threadIdx.x;
    const int wave = tid >> 6, lane = tid & 63;
    const int wm = wave >> 1, wn = wave & 1;
    const int quad = lane >> 4, r = lane & 15;
    const int row0 = blockIdx.x * 128;
    const int c0   = blockIdx.y * 128;

    f32x4 acc[4][4];
    #pragma unroll
    for (int i = 0; i < 4; ++i)
        #pragma unroll
        for (int j = 0; j < 4; ++j) acc[i][j] = (f32x4)0.f;

    const char* Ab = (const char*)Ob;
    const char* Bb = (const char*)Wob;

    for (int k0 = 0; k0 < 512; k0 += 32) {
        __syncthreads();
        #pragma unroll
        for (int q = 0; q < 2; ++q) {
            const int li = q * 4096 + wave * 1024 + lane * 16;
            const int rr = li >> 6, off = li & 63;
            gload_lds16(Ab + (size_t)(row0 + rr) * 1024 + k0 * 2 + off,
                        (char*)Als + (q * 4096 + wave * 1024));
            gload_lds16(Bb + (size_t)(c0 + rr) * 1024 + k0 * 2 + off,
                        (char*)Bls + (q * 4096 + wave * 1024));
        }
        __syncthreads();

        bf16x8 af[4], bf[4];
        #pragma unroll
        for (int i = 0; i < 4; ++i)
            af[i] = *(const bf16x8*)(&Als[(wm * 64 + i * 16 + r) * 32 + quad * 8]);
        #pragma unroll
        for (int j = 0; j < 4; ++j)
            bf[j] = *(const bf16x8*)(&Bls[(wn * 64 + j * 16 + r) * 32 + quad * 8]);
        #pragma unroll
        for (int i = 0; i < 4; ++i)
            #pragma unroll
            for (int j = 0; j < 4; ++j)
                acc[i][j] = __builtin_amdgcn_mfma_f32_16x16x32_bf16(af[i], bf[j], acc[i][j], 0, 0, 0);
    }

    #pragma unroll
    for (int i = 0; i < 4; ++i) {
        #pragma unroll
        for (int j = 0; j < 4; ++j) {
            const int colg = c0 + wn * 64 + j * 16 + r;
            const float bb = bout[colg];
            #pragma unroll
            for (int reg = 0; reg < 4; ++reg) {
                const int row = row0 + wm * 64 + i * 16 + quad * 4 + reg;
                out[((size_t)row << 9) + colg] = acc[i][j][reg] + bb;
            }
        }
    }
}

extern "C" void kernel_launch(void* const* d_in, const int* in_sizes, int n_in,
                              void* d_out, int out_size, void* d_ws, size_t ws_size,
                              hipStream_t stream)
{
    const float* x    = (const float*)d_in[0];
    const int*   idx  = (const int*)  d_in[1];
    const float* Wq   = (const float*)d_in[2];
    const float* Wk   = (const float*)d_in[3];
    const float* Wv   = (const float*)d_in[4];
    const float* Wout = (const float*)d_in[5];
    const float* bout = (const float*)d_in[6];

    char* ws = (char*)d_ws;
    float*          Qb  = (float*)(ws);                       // 33554432 B
    float*          Kb  = (float*)(ws + 33554432);            // 33554432 B
    float*          Vb  = (float*)(ws + 67108864);            // 33554432 B
    unsigned short* Xb  = (unsigned short*)(ws + 100663296);  // 16777216 B; aliased as Ob after gemm_qkv
    unsigned short* Ob  = Xb;
    unsigned short* Wfb = (unsigned short*)(ws + 117440512);  // 1572864 B  (Wq|Wk|Wv rows)
    unsigned short* Wob = (unsigned short*)(ws + 119013376);  // 524288 B
    float* out = (float*)d_out;

    cvt_x<<<8192, 256, 0, stream>>>(x, Xb);
    cvt_w<<<1024, 256, 0, stream>>>(Wq, Wk, Wv, Wout, Wfb, Wob);

    dim3 g1(BN / 128, 1536 / 128);
    gemm_qkv<<<g1, 256, 0, stream>>>(Xb, Wfb, Qb, Kb, Vb);

    ln_qk<<<BHN / 4, 256, 0, stream>>>(Qb, Kb);
    attn <<<BHN / 4, 256, 0, stream>>>(Qb, Kb, Vb, idx, Ob);

    dim3 g2(BN / 128, 512 / 128);
    gemm_out<<<g2, 256, 0, stream>>>(Ob, Wob, bout, out);
}

// Round 3
// 233.751 us; speedup vs baseline: 5.8950x; 2.2038x over previous
//
#include <hip/hip_runtime.h>
#include <hip/hip_bf16.h>
#include <math.h>

#define BB 2
#define NN 8192
#define DD 512
#define HH 8
#define DK 64
#define KNB 32
#define BN (BB*NN)          // 16384 rows
#define BHN (BB*HH*NN)      // 131072 (b,h,n) tuples

typedef __attribute__((ext_vector_type(8))) short bf16x8;   // 8 bf16 in 4 VGPRs
typedef __attribute__((ext_vector_type(8))) unsigned short us8;
typedef __attribute__((ext_vector_type(4))) float f32x4;

__device__ __forceinline__ float bf2f(unsigned short u) {
    return __uint_as_float(((unsigned)u) << 16);
}
__device__ __forceinline__ unsigned short f2bf(float f) {
    return __bfloat16_as_ushort(__float2bfloat16(f));   // RNE
}

// async global->LDS, 16B per lane. LDS dest must be wave-uniform base; HW adds lane*16.
__device__ __forceinline__ void gload_lds16(const void* gptr, void* lptr) {
    __builtin_amdgcn_global_load_lds(
        (const __attribute__((address_space(1))) unsigned int*)gptr,
        (__attribute__((address_space(3))) unsigned int*)lptr,
        16, 0, 0);
}

// ---------------- fp32 -> bf16 converters ----------------
__global__ __launch_bounds__(256) void cvt_x(const float* __restrict__ in,
                                             unsigned short* __restrict__ out) {
    const int i = (blockIdx.x * 256 + threadIdx.x) * 4;   // over BN*DD = 8388608
    const float4 v = *(const float4*)(in + i);
    ushort4 u;
    u.x = f2bf(v.x); u.y = f2bf(v.y); u.z = f2bf(v.z); u.w = f2bf(v.w);
    *(ushort4*)(out + i) = u;
}

__global__ __launch_bounds__(256) void cvt_w(const float* __restrict__ Wq, const float* __restrict__ Wk,
                                             const float* __restrict__ Wv, const float* __restrict__ Wo,
                                             unsigned short* __restrict__ Wfb,
                                             unsigned short* __restrict__ Wob) {
    const int e = (blockIdx.x * 256 + threadIdx.x) * 4;   // over 4*262144
    const int t = e >> 18;
    const int off = e & 262143;
    const float* src = (t == 0) ? Wq : (t == 1) ? Wk : (t == 2) ? Wv : Wo;
    unsigned short* dst = (t < 3) ? (Wfb + (size_t)t * 262144) : Wob;
    const float4 v = *(const float4*)(src + off);
    ushort4 u;
    u.x = f2bf(v.x); u.y = f2bf(v.y); u.z = f2bf(v.z); u.w = f2bf(v.w);
    *(ushort4*)(dst + off) = u;
}

// ---------------- Kernel 1: fused QKV projection + LayerNorm, bf16 MFMA ----------------
// C[row, c] = sum_d X[row,d] * W[c,d], M=16384, N=1536 (Q|K|V), K=512.
// Each wave's 64 columns = exactly one head's 64 dims, so per-row LayerNorm
// (for Q,K) reduces across 4 j-regs locally + shfl_xor{1,2,4,8} within the quad.
// Output: Q,K normalized bf16; V raw bf16; (b,h,n,d) layout.
__global__ __launch_bounds__(256) void gemm_qkv(
    const unsigned short* __restrict__ Xb, const unsigned short* __restrict__ Wfb,
    unsigned short* __restrict__ Qh, unsigned short* __restrict__ Kh,
    unsigned short* __restrict__ Vh)
{
    __shared__ unsigned short Als[128 * 32];   // 8 KB
    __shared__ unsigned short Bls[128 * 32];   // 8 KB
    const int tid  = threadIdx.x;
    const int wave = tid >> 6, lane = tid & 63;
    const int wm = wave >> 1, wn = wave & 1;
    const int quad = lane >> 4, r = lane & 15;
    const int row0 = blockIdx.x * 128;
    const int c0   = blockIdx.y * 128;        // 128 | 512 so tile is within one tensor

    f32x4 acc[4][4];
    #pragma unroll
    for (int i = 0; i < 4; ++i)
        #pragma unroll
        for (int j = 0; j < 4; ++j) acc[i][j] = (f32x4)0.f;

    const char* Ab = (const char*)Xb;
    const char* Bb = (const char*)Wfb;

    for (int k0 = 0; k0 < 512; k0 += 32) {
        __syncthreads();
        #pragma unroll
        for (int q = 0; q < 2; ++q) {
            const int li = q * 4096 + wave * 1024 + lane * 16;
            const int rr = li >> 6, off = li & 63;
            gload_lds16(Ab + (size_t)(row0 + rr) * 1024 + k0 * 2 + off,
                        (char*)Als + (q * 4096 + wave * 1024));
            gload_lds16(Bb + (size_t)(c0 + rr) * 1024 + k0 * 2 + off,
                        (char*)Bls + (q * 4096 + wave * 1024));
        }
        __syncthreads();

        bf16x8 af[4], bf[4];
        #pragma unroll
        for (int i = 0; i < 4; ++i)
            af[i] = *(const bf16x8*)(&Als[(wm * 64 + i * 16 + r) * 32 + quad * 8]);
        #pragma unroll
        for (int j = 0; j < 4; ++j)
            bf[j] = *(const bf16x8*)(&Bls[(wn * 64 + j * 16 + r) * 32 + quad * 8]);
        #pragma unroll
        for (int i = 0; i < 4; ++i)
            #pragma unroll
            for (int j = 0; j < 4; ++j)
                acc[i][j] = __builtin_amdgcn_mfma_f32_16x16x32_bf16(af[i], bf[j], acc[i][j], 0, 0, 0);
    }

    const int tensor = c0 >> 9;   // block-uniform: 0=Q 1=K 2=V
    unsigned short* OutH = (tensor == 0) ? Qh : (tensor == 1) ? Kh : Vh;

    // Per-row LayerNorm stats for Q,K. Row (i,quad,reg) has its 64 dims in
    // 4 j-regs x 16 r-lanes (quad-invariant under xor 1,2,4,8).
    float mu[4][4], rs[4][4];
    if (tensor < 2) {
        #pragma unroll
        for (int i = 0; i < 4; ++i) {
            #pragma unroll
            for (int reg = 0; reg < 4; ++reg) {
                float sm = acc[i][0][reg] + acc[i][1][reg] + acc[i][2][reg] + acc[i][3][reg];
                sm += __shfl_xor(sm, 1); sm += __shfl_xor(sm, 2);
                sm += __shfl_xor(sm, 4); sm += __shfl_xor(sm, 8);
                const float muv = sm * (1.f / 64.f);
                float qv = 0.f;
                #pragma unroll
                for (int j = 0; j < 4; ++j) {
                    const float dv = acc[i][j][reg] - muv;
                    qv = fmaf(dv, dv, qv);
                }
                qv += __shfl_xor(qv, 1); qv += __shfl_xor(qv, 2);
                qv += __shfl_xor(qv, 4); qv += __shfl_xor(qv, 8);
                mu[i][reg] = muv;
                rs[i][reg] = rsqrtf(qv * (1.f / 64.f) + 1e-5f);
            }
        }
    }

    // C/D layout col=lane&15, row=quad*4+reg (verified m89).
    #pragma unroll
    for (int i = 0; i < 4; ++i) {
        #pragma unroll
        for (int j = 0; j < 4; ++j) {
            const int cc = (c0 & 511) + wn * 64 + j * 16 + r;
            const int h = cc >> 6, d = cc & 63;
            #pragma unroll
            for (int reg = 0; reg < 4; ++reg) {
                const int row = row0 + wm * 64 + i * 16 + quad * 4 + reg;
                const int b = row >> 13, n = row & 8191;
                float v = acc[i][j][reg];
                if (tensor < 2) v = (v - mu[i][reg]) * rs[i][reg];
                OutH[(((size_t)(b * HH + h) * NN + n) << 6) + d] = f2bf(v);
            }
        }
    }
}

// ---------------- Kernel 2: gather-attention (bf16 in, fp32 math, bf16 out) ----------------
// One wave per (b,h,n). Score phase: 64 lanes = 32 neighbors x 2 half-rows of 32.
// V phase fully unrolled; readlane->SGPR broadcast makes all 32 row-loads independent.
// XCD swizzle: physical block p -> logical (p&7)*4096 + (p>>3), so each XCD streams
// contiguous n within ~2 (b,h) slabs (K+V bf16 = 4 MB, fits one XCD L2).
__global__ __launch_bounds__(256) void attn(
    const unsigned short* __restrict__ Qh, const unsigned short* __restrict__ Kh,
    const unsigned short* __restrict__ Vh,
    const int* __restrict__ idx, unsigned short* __restrict__ Ob)
{
    const int p = blockIdx.x;                       // 0..32767
    const int L = ((p & 7) << 12) | (p >> 3);       // XCD-contiguous logical id
    const int wid  = L * 4 + (threadIdx.x >> 6);    // 0..BHN-1
    const int lane = threadIdx.x & 63;
    const int bh = wid >> 13;
    const int n  = wid & 8191;
    const size_t base = (size_t)bh * NN * DK;

    const int k    = lane >> 1;
    const int half = lane & 1;
    const int g    = idx[n * KNB + k];              // pair-duplicated

    // half-row dot: 32 elements each
    const us8* q8 = (const us8*)(Qh + base + ((size_t)n << 6) + half * 32);
    const us8* k8 = (const us8*)(Kh + base + ((size_t)g << 6) + half * 32);
    float acc = 0.f;
    #pragma unroll
    for (int c = 0; c < 4; ++c) {
        const us8 qa = q8[c], ka = k8[c];
        #pragma unroll
        for (int e = 0; e < 8; ++e)
            acc = fmaf(bf2f(qa[e]), bf2f(ka[e]), acc);
    }
    float s = (acc + __shfl_xor(acc, 1)) * 0.125f;  // 1/sqrt(64)

    // softmax over the 32 distinct neighbors (values pair-duplicated):
    // xor over {2,4,8,16,32} touches each distinct k exactly once.
    float m = s;
    #pragma unroll
    for (int off = 2; off <= 32; off <<= 1) m = fmaxf(m, __shfl_xor(m, off));
    const float e = __expf(s - m);
    float tot = e;
    #pragma unroll
    for (int off = 2; off <= 32; off <<= 1) tot += __shfl_xor(tot, off);
    const float pr = e / tot;

    // V accumulation: lane d accumulates sum_k p_k * V[g_k][d].
    float o = 0.f;
    #pragma unroll
    for (int kk = 0; kk < 32; ++kk) {
        const int   gk = __builtin_amdgcn_readlane(g, kk * 2);
        const float pk = __uint_as_float(
            __builtin_amdgcn_readlane(__float_as_uint(pr), kk * 2));
        o = fmaf(pk, bf2f(Vh[base + ((size_t)gk << 6) + lane]), o);
    }
    const int b = bh >> 3, h = bh & 7;
    Ob[((size_t)(b * NN + n)) * DD + h * DK + lane] = f2bf(o);
}

// ---------------- Kernel 3: output projection, bf16 MFMA ----------------
__global__ __launch_bounds__(256) void gemm_out(
    const unsigned short* __restrict__ Ob, const unsigned short* __restrict__ Wob,
    const float* __restrict__ bout, float* __restrict__ out)
{
    __shared__ unsigned short Als[128 * 32];
    __shared__ unsigned short Bls[128 * 32];
    const int tid  = threadIdx.x;
    const int wave = tid >> 6, lane = tid & 63;
    const int wm = wave >> 1, wn = wave & 1;
    const int quad = lane >> 4, r = lane & 15;
    const int row0 = blockIdx.x * 128;
    const int c0   = blockIdx.y * 128;

    f32x4 acc[4][4];
    #pragma unroll
    for (int i = 0; i < 4; ++i)
        #pragma unroll
        for (int j = 0; j < 4; ++j) acc[i][j] = (f32x4)0.f;

    const char* Ab = (const char*)Ob;
    const char* Bb = (const char*)Wob;

    for (int k0 = 0; k0 < 512; k0 += 32) {
        __syncthreads();
        #pragma unroll
        for (int q = 0; q < 2; ++q) {
            const int li = q * 4096 + wave * 1024 + lane * 16;
            const int rr = li >> 6, off = li & 63;
            gload_lds16(Ab + (size_t)(row0 + rr) * 1024 + k0 * 2 + off,
                        (char*)Als + (q * 4096 + wave * 1024));
            gload_lds16(Bb + (size_t)(c0 + rr) * 1024 + k0 * 2 + off,
                        (char*)Bls + (q * 4096 + wave * 1024));
        }
        __syncthreads();

        bf16x8 af[4], bf[4];
        #pragma unroll
        for (int i = 0; i < 4; ++i)
            af[i] = *(const bf16x8*)(&Als[(wm * 64 + i * 16 + r) * 32 + quad * 8]);
        #pragma unroll
        for (int j = 0; j < 4; ++j)
            bf[j] = *(const bf16x8*)(&Bls[(wn * 64 + j * 16 + r) * 32 + quad * 8]);
        #pragma unroll
        for (int i = 0; i < 4; ++i)
            #pragma unroll
            for (int j = 0; j < 4; ++j)
                acc[i][j] = __builtin_amdgcn_mfma_f32_16x16x32_bf16(af[i], bf[j], acc[i][j], 0, 0, 0);
    }

    #pragma unroll
    for (int i = 0; i < 4; ++i) {
        #pragma unroll
        for (int j = 0; j < 4; ++j) {
            const int colg = c0 + wn * 64 + j * 16 + r;
            const float bb = bout[colg];
            #pragma unroll
            for (int reg = 0; reg < 4; ++reg) {
                const int row = row0 + wm * 64 + i * 16 + quad * 4 + reg;
                out[((size_t)row << 9) + colg] = acc[i][j][reg] + bb;
            }
        }
    }
}

extern "C" void kernel_launch(void* const* d_in, const int* in_sizes, int n_in,
                              void* d_out, int out_size, void* d_ws, size_t ws_size,
                              hipStream_t stream)
{
    const float* x    = (const float*)d_in[0];
    const int*   idx  = (const int*)  d_in[1];
    const float* Wq   = (const float*)d_in[2];
    const float* Wk   = (const float*)d_in[3];
    const float* Wv   = (const float*)d_in[4];
    const float* Wout = (const float*)d_in[5];
    const float* bout = (const float*)d_in[6];

    char* ws = (char*)d_ws;
    unsigned short* Qh  = (unsigned short*)(ws);              // 16777216 B
    unsigned short* Kh  = (unsigned short*)(ws + 16777216);   // 16777216 B
    unsigned short* Vh  = (unsigned short*)(ws + 33554432);   // 16777216 B
    unsigned short* Xb  = (unsigned short*)(ws + 50331648);   // 16777216 B; aliased as Ob
    unsigned short* Ob  = Xb;
    unsigned short* Wfb = (unsigned short*)(ws + 67108864);   // 1572864 B (Wq|Wk|Wv rows)
    unsigned short* Wob = (unsigned short*)(ws + 68681728);   // 524288 B
    float* out = (float*)d_out;

    cvt_x<<<8192, 256, 0, stream>>>(x, Xb);
    cvt_w<<<1024, 256, 0, stream>>>(Wq, Wk, Wv, Wout, Wfb, Wob);

    dim3 g1(BN / 128, 1536 / 128);
    gemm_qkv<<<g1, 256, 0, stream>>>(Xb, Wfb, Qh, Kh, Vh);

    attn<<<BHN / 4, 256, 0, stream>>>(Qh, Kh, Vh, idx, Ob);

    dim3 g2(BN / 128, 512 / 128);
    gemm_out<<<g2, 256, 0, stream>>>(Ob, Wob, bout, out);
}

// Round 4
// 229.522 us; speedup vs baseline: 6.0036x; 1.0184x over previous
//
#include <hip/hip_runtime.h>
#include <hip/hip_bf16.h>
#include <math.h>

#define BB 2
#define NN 8192
#define DD 512
#define HH 8
#define DK 64
#define KNB 32
#define BN (BB*NN)          // 16384 rows
#define BHN (BB*HH*NN)      // 131072 (b,h,n) tuples

typedef __attribute__((ext_vector_type(8))) _Float16 f16x8;   // 8 f16 in 4 VGPRs
typedef __attribute__((ext_vector_type(2))) _Float16 f16x2;
typedef __attribute__((ext_vector_type(4))) float f32x4;

#if __has_builtin(__builtin_amdgcn_fdot2)
#define HAS_FDOT2 1
#endif

__device__ __forceinline__ unsigned short f2h(float f) {
    return __builtin_bit_cast(unsigned short, (_Float16)f);
}
__device__ __forceinline__ f16x2 u2h2(unsigned u) {
    return __builtin_bit_cast(f16x2, u);
}
__device__ __forceinline__ float h2f_lo(unsigned u) {
    return (float)__builtin_bit_cast(_Float16, (unsigned short)(u & 0xffffu));
}
__device__ __forceinline__ float h2f_hi(unsigned u) {
    return (float)__builtin_bit_cast(_Float16, (unsigned short)(u >> 16));
}
// dot of packed f16 pairs with fp32 accumulate
__device__ __forceinline__ float dot2h(unsigned a, unsigned b, float c) {
#ifdef HAS_FDOT2
    return __builtin_amdgcn_fdot2(u2h2(a), u2h2(b), c, false);
#else
    c = fmaf(h2f_lo(a), h2f_lo(b), c);
    return fmaf(h2f_hi(a), h2f_hi(b), c);
#endif
}

// async global->LDS, 16B per lane. LDS dest must be wave-uniform base; HW adds lane*16.
__device__ __forceinline__ void gload_lds16(const void* gptr, void* lptr) {
    __builtin_amdgcn_global_load_lds(
        (const __attribute__((address_space(1))) unsigned int*)gptr,
        (__attribute__((address_space(3))) unsigned int*)lptr,
        16, 0, 0);
}

// ---------------- fp32 -> f16 converter (x + all weights, one launch) ----------------
// blocks 0..8191: x (8388608 elems). blocks 8192..9215: weights (4*262144 elems).
__global__ __launch_bounds__(256) void cvt_all(
    const float* __restrict__ x,
    const float* __restrict__ Wq, const float* __restrict__ Wk,
    const float* __restrict__ Wv, const float* __restrict__ Wo,
    unsigned short* __restrict__ Xb, unsigned short* __restrict__ Wfb,
    unsigned short* __restrict__ Wob)
{
    const int blk = blockIdx.x;
    const float* src;
    unsigned short* dst;
    int off;
    if (blk < 8192) {
        off = (blk * 256 + threadIdx.x) * 4;
        src = x; dst = Xb;
    } else {
        const int e = ((blk - 8192) * 256 + threadIdx.x) * 4;   // over 4*262144
        const int t = e >> 18;
        off = e & 262143;
        src = (t == 0) ? Wq : (t == 1) ? Wk : (t == 2) ? Wv : Wo;
        dst = (t < 3) ? (Wfb + (size_t)t * 262144) : Wob;
    }
    const float4 v = *(const float4*)(src + off);
    ushort4 u;
    u.x = f2h(v.x); u.y = f2h(v.y); u.z = f2h(v.z); u.w = f2h(v.w);
    *(ushort4*)(dst + off) = u;
}

// ---------------- Kernel 1: fused QKV projection + LayerNorm, f16 MFMA ----------------
// C[row, c] = sum_d X[row,d] * W[c,d], M=16384, N=1536 (Q|K|V), K=512.
// Each wave's 64 columns = exactly one head's 64 dims, so per-row LayerNorm
// (for Q,K) reduces across 4 j-regs locally + shfl_xor{1,2,4,8} within the quad.
// Output: Q,K normalized f16; V raw f16; (b,h,n,d) layout.
__global__ __launch_bounds__(256) void gemm_qkv(
    const unsigned short* __restrict__ Xb, const unsigned short* __restrict__ Wfb,
    unsigned short* __restrict__ Qh, unsigned short* __restrict__ Kh,
    unsigned short* __restrict__ Vh)
{
    __shared__ unsigned short Als[128 * 32];   // 8 KB
    __shared__ unsigned short Bls[128 * 32];   // 8 KB
    const int tid  = threadIdx.x;
    const int wave = tid >> 6, lane = tid & 63;
    const int wm = wave >> 1, wn = wave & 1;
    const int quad = lane >> 4, r = lane & 15;
    const int row0 = blockIdx.x * 128;
    const int c0   = blockIdx.y * 128;        // 128 | 512 so tile is within one tensor

    f32x4 acc[4][4];
    #pragma unroll
    for (int i = 0; i < 4; ++i)
        #pragma unroll
        for (int j = 0; j < 4; ++j) acc[i][j] = (f32x4)0.f;

    const char* Ab = (const char*)Xb;
    const char* Bb = (const char*)Wfb;

    for (int k0 = 0; k0 < 512; k0 += 32) {
        __syncthreads();
        #pragma unroll
        for (int q = 0; q < 2; ++q) {
            const int li = q * 4096 + wave * 1024 + lane * 16;
            const int rr = li >> 6, off = li & 63;
            gload_lds16(Ab + (size_t)(row0 + rr) * 1024 + k0 * 2 + off,
                        (char*)Als + (q * 4096 + wave * 1024));
            gload_lds16(Bb + (size_t)(c0 + rr) * 1024 + k0 * 2 + off,
                        (char*)Bls + (q * 4096 + wave * 1024));
        }
        __syncthreads();

        f16x8 af[4], bf[4];
        #pragma unroll
        for (int i = 0; i < 4; ++i)
            af[i] = *(const f16x8*)(&Als[(wm * 64 + i * 16 + r) * 32 + quad * 8]);
        #pragma unroll
        for (int j = 0; j < 4; ++j)
            bf[j] = *(const f16x8*)(&Bls[(wn * 64 + j * 16 + r) * 32 + quad * 8]);
        #pragma unroll
        for (int i = 0; i < 4; ++i)
            #pragma unroll
            for (int j = 0; j < 4; ++j)
                acc[i][j] = __builtin_amdgcn_mfma_f32_16x16x32_f16(af[i], bf[j], acc[i][j], 0, 0, 0);
    }

    const int tensor = c0 >> 9;   // block-uniform: 0=Q 1=K 2=V
    unsigned short* OutH = (tensor == 0) ? Qh : (tensor == 1) ? Kh : Vh;

    // Per-row LayerNorm stats for Q,K. Row (i,quad,reg) has its 64 dims in
    // 4 j-regs x 16 r-lanes (quad-invariant under xor 1,2,4,8).
    float mu[4][4], rs[4][4];
    if (tensor < 2) {
        #pragma unroll
        for (int i = 0; i < 4; ++i) {
            #pragma unroll
            for (int reg = 0; reg < 4; ++reg) {
                float sm = acc[i][0][reg] + acc[i][1][reg] + acc[i][2][reg] + acc[i][3][reg];
                sm += __shfl_xor(sm, 1); sm += __shfl_xor(sm, 2);
                sm += __shfl_xor(sm, 4); sm += __shfl_xor(sm, 8);
                const float muv = sm * (1.f / 64.f);
                float qv = 0.f;
                #pragma unroll
                for (int j = 0; j < 4; ++j) {
                    const float dv = acc[i][j][reg] - muv;
                    qv = fmaf(dv, dv, qv);
                }
                qv += __shfl_xor(qv, 1); qv += __shfl_xor(qv, 2);
                qv += __shfl_xor(qv, 4); qv += __shfl_xor(qv, 8);
                mu[i][reg] = muv;
                rs[i][reg] = rsqrtf(qv * (1.f / 64.f) + 1e-5f);
            }
        }
    }

    // C/D layout col=lane&15, row=quad*4+reg (verified m89).
    #pragma unroll
    for (int i = 0; i < 4; ++i) {
        #pragma unroll
        for (int j = 0; j < 4; ++j) {
            const int cc = (c0 & 511) + wn * 64 + j * 16 + r;
            const int h = cc >> 6, d = cc & 63;
            #pragma unroll
            for (int reg = 0; reg < 4; ++reg) {
                const int row = row0 + wm * 64 + i * 16 + quad * 4 + reg;
                const int b = row >> 13, n = row & 8191;
                float v = acc[i][j][reg];
                if (tensor < 2) v = (v - mu[i][reg]) * rs[i][reg];
                OutH[(((size_t)(b * HH + h) * NN + n) << 6) + d] = f2h(v);
            }
        }
    }
}

// ---------------- Kernel 2: gather-attention (f16 in, fp32 accum, f16 out) ----------------
// One wave per (b,h,n). Score phase: 64 lanes = 32 neighbors x 2 half-rows of 32,
// v_dot2_f32_f16 on packed pairs. V phase: 2 neighbors per iter; g-pair and
// p-pair packed in one VGPR each -> 1 readlane per pair; packed-V fdot2.
// XCD swizzle: physical block p -> logical (p&7)*4096 + (p>>3).
__global__ __launch_bounds__(256) void attn(
    const unsigned short* __restrict__ Qh, const unsigned short* __restrict__ Kh,
    const unsigned short* __restrict__ Vh,
    const int* __restrict__ idx, unsigned short* __restrict__ Ob)
{
    const int p = blockIdx.x;                       // 0..32767
    const int L = ((p & 7) << 12) | (p >> 3);       // XCD-contiguous logical id
    const int wid  = L * 4 + (threadIdx.x >> 6);    // 0..BHN-1
    const int lane = threadIdx.x & 63;
    const int bh = wid >> 13;
    const int n  = wid & 8191;
    const size_t base = (size_t)bh * NN * DK;

    const int k    = lane >> 1;
    const int half = lane & 1;
    const int g    = idx[n * KNB + k];              // pair-duplicated

    // half-row dot: 32 elements each, as 16 packed f16 pairs
    const uint4* q4 = (const uint4*)(Qh + base + ((size_t)n << 6) + half * 32);
    const uint4* k4 = (const uint4*)(Kh + base + ((size_t)g << 6) + half * 32);
    float acc = 0.f;
    #pragma unroll
    for (int c = 0; c < 4; ++c) {
        const uint4 qa = q4[c], ka = k4[c];
        acc = dot2h(qa.x, ka.x, acc);
        acc = dot2h(qa.y, ka.y, acc);
        acc = dot2h(qa.z, ka.z, acc);
        acc = dot2h(qa.w, ka.w, acc);
    }
    float s = (acc + __shfl_xor(acc, 1)) * 0.125f;  // 1/sqrt(64)

    // softmax over 32 distinct neighbors (values pair-duplicated):
    float m = s;
    #pragma unroll
    for (int off = 2; off <= 32; off <<= 1) m = fmaxf(m, __shfl_xor(m, off));
    const float e = __expf(s - m);
    float tot = e;
    #pragma unroll
    for (int off = 2; off <= 32; off <<= 1) tot += __shfl_xor(tot, off);
    const float pr = e / tot;

    // Pack neighbor-pair (p, g) so the V loop needs 1 readlane each per 2 neighbors.
    // Lane 4j: pp = p_{2j} | p_{2j+1}<<16 (f16), gg = g_{2j} | g_{2j+1}<<16.
    const unsigned prh = (unsigned)f2h(pr);
    const unsigned pp = prh | (((unsigned)__shfl_xor((int)prh, 2)) << 16);
    const unsigned gg = (unsigned)g | (((unsigned)__shfl_xor(g, 2)) << 16);

    // V accumulation: lane d accumulates sum_k p_k * V[g_k][d].
    float o = 0.f;
    #pragma unroll
    for (int j = 0; j < 16; ++j) {
        const unsigned gpair = (unsigned)__builtin_amdgcn_readlane((int)gg, j * 4);
        const unsigned ppair = (unsigned)__builtin_amdgcn_readlane((int)pp, j * 4);
        const int g0 = (int)(gpair & 0xffffu), g1 = (int)(gpair >> 16);
        const unsigned v0 = Vh[base + ((size_t)g0 << 6) + lane];
        const unsigned v1 = Vh[base + ((size_t)g1 << 6) + lane];
        o = dot2h(v0 | (v1 << 16), ppair, o);
    }
    const int b = bh >> 3, h = bh & 7;
    Ob[((size_t)(b * NN + n)) * DD + h * DK + lane] = f2h(o);
}

// ---------------- Kernel 3: output projection, f16 MFMA ----------------
__global__ __launch_bounds__(256) void gemm_out(
    const unsigned short* __restrict__ Ob, const unsigned short* __restrict__ Wob,
    const float* __restrict__ bout, float* __restrict__ out)
{
    __shared__ unsigned short Als[128 * 32];
    __shared__ unsigned short Bls[128 * 32];
    const int tid  = threadIdx.x;
    const int wave = tid >> 6, lane = tid & 63;
    const int wm = wave >> 1, wn = wave & 1;
    const int quad = lane >> 4, r = lane & 15;
    const int row0 = blockIdx.x * 128;
    const int c0   = blockIdx.y * 128;

    f32x4 acc[4][4];
    #pragma unroll
    for (int i = 0; i < 4; ++i)
        #pragma unroll
        for (int j = 0; j < 4; ++j) acc[i][j] = (f32x4)0.f;

    const char* Ab = (const char*)Ob;
    const char* Bb = (const char*)Wob;

    for (int k0 = 0; k0 < 512; k0 += 32) {
        __syncthreads();
        #pragma unroll
        for (int q = 0; q < 2; ++q) {
            const int li = q * 4096 + wave * 1024 + lane * 16;
            const int rr = li >> 6, off = li & 63;
            gload_lds16(Ab + (size_t)(row0 + rr) * 1024 + k0 * 2 + off,
                        (char*)Als + (q * 4096 + wave * 1024));
            gload_lds16(Bb + (size_t)(c0 + rr) * 1024 + k0 * 2 + off,
                        (char*)Bls + (q * 4096 + wave * 1024));
        }
        __syncthreads();

        f16x8 af[4], bf[4];
        #pragma unroll
        for (int i = 0; i < 4; ++i)
            af[i] = *(const f16x8*)(&Als[(wm * 64 + i * 16 + r) * 32 + quad * 8]);
        #pragma unroll
        for (int j = 0; j < 4; ++j)
            bf[j] = *(const f16x8*)(&Bls[(wn * 64 + j * 16 + r) * 32 + quad * 8]);
        #pragma unroll
        for (int i = 0; i < 4; ++i)
            #pragma unroll
            for (int j = 0; j < 4; ++j)
                acc[i][j] = __builtin_amdgcn_mfma_f32_16x16x32_f16(af[i], bf[j], acc[i][j], 0, 0, 0);
    }

    #pragma unroll
    for (int i = 0; i < 4; ++i) {
        #pragma unroll
        for (int j = 0; j < 4; ++j) {
            const int colg = c0 + wn * 64 + j * 16 + r;
            const float bb = bout[colg];
            #pragma unroll
            for (int reg = 0; reg < 4; ++reg) {
                const int row = row0 + wm * 64 + i * 16 + quad * 4 + reg;
                out[((size_t)row << 9) + colg] = acc[i][j][reg] + bb;
            }
        }
    }
}

extern "C" void kernel_launch(void* const* d_in, const int* in_sizes, int n_in,
                              void* d_out, int out_size, void* d_ws, size_t ws_size,
                              hipStream_t stream)
{
    const float* x    = (const float*)d_in[0];
    const int*   idx  = (const int*)  d_in[1];
    const float* Wq   = (const float*)d_in[2];
    const float* Wk   = (const float*)d_in[3];
    const float* Wv   = (const float*)d_in[4];
    const float* Wout = (const float*)d_in[5];
    const float* bout = (const float*)d_in[6];

    char* ws = (char*)d_ws;
    unsigned short* Qh  = (unsigned short*)(ws);              // 16777216 B
    unsigned short* Kh  = (unsigned short*)(ws + 16777216);   // 16777216 B
    unsigned short* Vh  = (unsigned short*)(ws + 33554432);   // 16777216 B
    unsigned short* Xb  = (unsigned short*)(ws + 50331648);   // 16777216 B; aliased as Ob
    unsigned short* Ob  = Xb;
    unsigned short* Wfb = (unsigned short*)(ws + 67108864);   // 1572864 B (Wq|Wk|Wv rows)
    unsigned short* Wob = (unsigned short*)(ws + 68681728);   // 524288 B
    float* out = (float*)d_out;

    cvt_all<<<9216, 256, 0, stream>>>(x, Wq, Wk, Wv, Wout, Xb, Wfb, Wob);

    dim3 g1(BN / 128, 1536 / 128);
    gemm_qkv<<<g1, 256, 0, stream>>>(Xb, Wfb, Qh, Kh, Vh);

    attn<<<BHN / 4, 256, 0, stream>>>(Qh, Kh, Vh, idx, Ob);

    dim3 g2(BN / 128, 512 / 128);
    gemm_out<<<g2, 256, 0, stream>>>(Ob, Wob, bout, out);
}